// Round 10
// baseline (393.748 us; speedup 1.0000x reference)
//
#include <hip/hip_runtime.h>
#include <hip/hip_bf16.h>
#include <stdint.h>

typedef unsigned short u16;
typedef short s16x8 __attribute__((ext_vector_type(8)));
typedef u16 u16x8 __attribute__((ext_vector_type(8)));
typedef u16 u16x4 __attribute__((ext_vector_type(4)));
typedef float f32x4 __attribute__((ext_vector_type(4)));

__device__ __forceinline__ u16 f2bf(float f) {
  union { float f; uint32_t u; } c; c.f = f;
  uint32_t u = c.u;
  u = u + 0x7fffu + ((u >> 16) & 1u);   // round-to-nearest-even
  return (u16)(u >> 16);
}
__device__ __forceinline__ float bf2f(u16 b) {
  union { uint32_t u; float f; } c; c.u = ((uint32_t)b) << 16;
  return c.f;
}

// async global->LDS, 16B per lane. LDS dest must be wave-uniform base + lane*16.
__device__ __forceinline__ void gld_lds16(const u16* g, u16* l) {
  __builtin_amdgcn_global_load_lds(
      (const __attribute__((address_space(1))) uint32_t*)g,
      (__attribute__((address_space(3))) uint32_t*)l,
      16, 0, 0);
}

// ---------------------------------------------------------------------------
// fp32 -> bf16 convert, 8 elems/thread
// ---------------------------------------------------------------------------
__global__ __launch_bounds__(256) void cvt_f32_to_bf16(
    const float* __restrict__ in, u16* __restrict__ out, long n8) {
  long i = (long)blockIdx.x * blockDim.x + threadIdx.x;
  if (i >= n8) return;
  const float4 a = ((const float4*)in)[i * 2];
  const float4 b = ((const float4*)in)[i * 2 + 1];
  u16x8 r;
  r[0] = f2bf(a.x); r[1] = f2bf(a.y); r[2] = f2bf(a.z); r[3] = f2bf(a.w);
  r[4] = f2bf(b.x); r[5] = f2bf(b.y); r[6] = f2bf(b.z); r[7] = f2bf(b.w);
  *(u16x8*)&out[i * 8] = r;
}

// 4 weight matrices (1024x1024 each) in one launch: blockIdx.y selects src
__global__ __launch_bounds__(256) void cvt_w4(
    const float* __restrict__ w0, const float* __restrict__ w1,
    const float* __restrict__ w2, const float* __restrict__ w3,
    u16* __restrict__ out) {
  const float* src = (blockIdx.y == 0) ? w0 : (blockIdx.y == 1) ? w1
                   : (blockIdx.y == 2) ? w2 : w3;
  const long i = (long)blockIdx.x * blockDim.x + threadIdx.x;
  const float4 a = ((const float4*)src)[i * 2];
  const float4 b = ((const float4*)src)[i * 2 + 1];
  u16x8 r;
  r[0] = f2bf(a.x); r[1] = f2bf(a.y); r[2] = f2bf(a.z); r[3] = f2bf(a.w);
  r[4] = f2bf(b.x); r[5] = f2bf(b.y); r[6] = f2bf(b.z); r[7] = f2bf(b.w);
  *(u16x8*)&out[(long)blockIdx.y * 1048576 + i * 8] = r;
}

// ---------------------------------------------------------------------------
// bf16 tiled transpose: in [z][R][C] -> out [z][C][R], 64x64 tiles
// ---------------------------------------------------------------------------
__global__ __launch_bounds__(256) void transpose64(
    const u16* __restrict__ in, u16* __restrict__ out, int R, int C) {
  __shared__ u16 t[64][66];
  const long ib = (long)blockIdx.z * (long)R * C;
  const int r0 = blockIdx.x * 64, c0 = blockIdx.y * 64;
  const int tid = threadIdx.x;
#pragma unroll
  for (int i = 0; i < 2; ++i) {
    const int ch = i * 256 + tid;
    const int r = ch >> 3, cc = ch & 7;
    const s16x8 v = *(const s16x8*)&in[ib + (long)(r0 + r) * C + c0 + cc * 8];
#pragma unroll
    for (int j = 0; j < 8; ++j) t[r][cc * 8 + j] = (u16)v[j];
  }
  __syncthreads();
#pragma unroll
  for (int i = 0; i < 2; ++i) {
    const int ch = i * 256 + tid;
    const int c = ch >> 3, rr = ch & 7;
    u16x8 r8;
#pragma unroll
    for (int j = 0; j < 8; ++j) r8[j] = t[rr * 8 + j][c];
    *(u16x8*)&out[ib + (long)(c0 + c) * R + r0 + rr * 8] = r8;
  }
}

// ---------------------------------------------------------------------------
// prep: wvec[g] = scale * sum_e Wk[e,g]*bq[e]   (blocks 0-3, coalesced over g)
//       bvo[f]  = sum_e Wo[f,e]*bv[e] + bo[f]   (blocks 4-7, row-stream f4)
// ---------------------------------------------------------------------------
__global__ __launch_bounds__(256) void prep_vec(
    const float* __restrict__ Wk, const float* __restrict__ bq,
    const float* __restrict__ Wo, const float* __restrict__ bv,
    const float* __restrict__ bo, float* __restrict__ wvec,
    float* __restrict__ bvo, float scale) {
  const int bi = blockIdx.x;
  if (bi < 4) {
    const int g = bi * 256 + threadIdx.x;
    float s = 0.f;
    for (int e = 0; e < 1024; ++e) s += Wk[(long)e * 1024 + g] * bq[e];
    wvec[g] = s * scale;
  } else {
    const int f = (bi - 4) * 256 + threadIdx.x;
    const float4* row = (const float4*)&Wo[(long)f * 1024];
    float s = 0.f;
    for (int e4 = 0; e4 < 256; ++e4) {
      const float4 x = row[e4];
      const float4 b4 = ((const float4*)bv)[e4];
      s += x.x * b4.x + x.y * b4.y + x.z * b4.z + x.w * b4.w;
    }
    bvo[f] = s + bo[f];
  }
}

// ---------------------------------------------------------------------------
// c[row] = dot(kvbf[row, :1024], wvec)  — 16 rows/block, wave-per-row slices
// ---------------------------------------------------------------------------
__global__ __launch_bounds__(256) void cgemv(
    const u16* __restrict__ kvbf, const float* __restrict__ wvec,
    float* __restrict__ c) {
  __shared__ float w[1024];
  const int tid = threadIdx.x;
#pragma unroll
  for (int i = 0; i < 4; ++i) w[i * 256 + tid] = wvec[i * 256 + tid];
  __syncthreads();
  const int lane = tid & 63, wv_ = tid >> 6;
  const long rowbase = (long)blockIdx.x * 16 + wv_ * 4;
#pragma unroll
  for (int r = 0; r < 4; ++r) {
    const long row = rowbase + r;
    const u16* p = &kvbf[row * 1024 + lane * 16];
    const u16x8 a = *(const u16x8*)p;
    const u16x8 b = *(const u16x8*)(p + 8);
    float s = 0.f;
#pragma unroll
    for (int j = 0; j < 8; ++j) s += bf2f(a[j]) * w[lane * 16 + j];
#pragma unroll
    for (int j = 0; j < 8; ++j) s += bf2f(b[j]) * w[lane * 16 + 8 + j];
#pragma unroll
    for (int off = 32; off >= 1; off >>= 1) s += __shfl_xor(s, off);
    if (lane == 0) c[row] = s;
  }
}

// ---------------------------------------------------------------------------
// row softmax over 2048 cols, bf16 in/out (in place), fp32 math.
// S already has -1e30 at masked positions (mask fused into QK epilogue).
// ---------------------------------------------------------------------------
__global__ __launch_bounds__(256) void softmax_rows(u16* __restrict__ S) {
  const long base = (long)blockIdx.x * 2048;
  const int tid = threadIdx.x;
  const int lane = tid & 63, wave = tid >> 6;
  u16x8 raw = *(const u16x8*)&S[base + tid * 8];
  float v[8];
#pragma unroll
  for (int j = 0; j < 8; ++j) v[j] = bf2f(raw[j]);
  float m = v[0];
#pragma unroll
  for (int j = 1; j < 8; ++j) m = fmaxf(m, v[j]);
#pragma unroll
  for (int off = 32; off >= 1; off >>= 1) m = fmaxf(m, __shfl_xor(m, off));
  __shared__ float red[8];
  if (lane == 0) red[wave] = m;
  __syncthreads();
  m = fmaxf(fmaxf(red[0], red[1]), fmaxf(red[2], red[3]));
  float s = 0.f;
#pragma unroll
  for (int j = 0; j < 8; ++j) { v[j] = __expf(v[j] - m); s += v[j]; }
#pragma unroll
  for (int off = 32; off >= 1; off >>= 1) s += __shfl_xor(s, off);
  if (lane == 0) red[4 + wave] = s;
  __syncthreads();
  s = (red[4] + red[5]) + (red[6] + red[7]);
  const float inv = 1.f / s;
#pragma unroll
  for (int j = 0; j < 8; ++j) raw[j] = f2bf(v[j] * inv);
  *(u16x8*)&S[base + tid * 8] = raw;
}

// ---------------------------------------------------------------------------
// 128x128x64 GEMM (bt), m97/m103 TLP structure (round-7/9 verified ~890 TF):
// 256 thr = 4 waves (2x2), single-buffered 32 KiB LDS, 2 barriers/K-tile,
// 5 blocks/CU via LDS limit; __launch_bounds__(256,4) (VGPR 64, no spill).
// T2 chunk-XOR swizzle (0 read conflicts), T1 XCD-bijective remap.
// MODE: 0 bf16 out; 1 f32 out; 3 transposed bf16 out [b][col][2048-row].
// bias[col] with per-batch stride sBias; optional fused mask (0 -> -1e30).
// ---------------------------------------------------------------------------
union __align__(16) SmemT {
  u16 stage[2][128 * 64];        // 32 KiB: A-tile, B-tile
  float epi[32 * 132];           // 16.9 KiB epilogue C-staging (quarter-tile)
};

__device__ __forceinline__ s16x8 ldsfrag(const u16* p, int r, int c8) {
  return *(const s16x8*)&p[r * 64 + ((c8 ^ (r & 7)) << 3)];
}

__device__ __forceinline__ void stage128(const u16* __restrict__ gb, int row0,
                                         int K, int k0, u16* lbuf, int tid) {
#pragma unroll
  for (int i = 0; i < 4; ++i) {
    const int f = i * 256 + tid;
    const int rl = f >> 3, s = f & 7;
    const int gc = (s ^ (rl & 7)) << 3;     // pre-swizzled global col chunk
    gld_lds16(gb + (long)(row0 + rl) * K + k0 + gc, lbuf + f * 8);
  }
}

template<bool HAS_BIAS, int MODE, bool HAS_MASK>
__global__ __launch_bounds__(256, 4) void gemm128(
    const u16* __restrict__ A, const u16* __restrict__ B,
    const float* __restrict__ bias, const int* __restrict__ mask,
    void* __restrict__ Cv,
    int M, int N, int K, long sA, long sB, long sC, long sMask, long sBias,
    float scale) {
  __shared__ SmemT sm;
  // T1 swizzle: dispatch id -> XCD-contiguous chunk (z-major, then m, then n)
  const int nx = gridDim.x, ny = gridDim.y;
  const int did = blockIdx.x + nx * (blockIdx.y + ny * blockIdx.z);
  const int cpx = (nx * ny * gridDim.z) >> 3;       // all grids %8 == 0
  const int nf = (did & 7) * cpx + (did >> 3);
  const int b = nf / (nx * ny);
  const int rr = nf % (nx * ny);
  const int bm = (rr / ny) * 128;
  const int bn = (rr % ny) * 128;

  const u16* Ab = A + (long)b * sA;
  const u16* Bb = B + (long)b * sB;
  const float* biasB = HAS_BIAS ? (bias + (long)b * sBias) : nullptr;
  const int tid = threadIdx.x;
  const int lane = tid & 63, wave = tid >> 6;
  const int wm = wave >> 1, wn = wave & 1;          // 2x2 waves, 64x64 each
  const int lr = lane & 15, lk = lane >> 4;
  const int NT = K >> 6;

  f32x4 acc[4][4] = {};

  for (int t = 0; t < NT; ++t) {
    stage128(Ab, bm, K, t << 6, sm.stage[0], tid);
    stage128(Bb, bn, K, t << 6, sm.stage[1], tid);
    asm volatile("s_waitcnt vmcnt(0)" ::: "memory");
    __syncthreads();
#pragma unroll
    for (int ks = 0; ks < 2; ++ks) {
      s16x8 af[4], bg[4];
#pragma unroll
      for (int mi = 0; mi < 4; ++mi)
        af[mi] = ldsfrag(sm.stage[0], wm * 64 + mi * 16 + lr, ks * 4 + lk);
#pragma unroll
      for (int ni = 0; ni < 4; ++ni)
        bg[ni] = ldsfrag(sm.stage[1], wn * 64 + ni * 16 + lr, ks * 4 + lk);
#pragma unroll
      for (int mi = 0; mi < 4; ++mi)
#pragma unroll
        for (int ni = 0; ni < 4; ++ni)
          acc[mi][ni] = __builtin_amdgcn_mfma_f32_16x16x32_bf16(
              af[mi], bg[ni], acc[mi][ni], 0, 0, 0);
    }
    __syncthreads();
  }

  // ---------------- epilogue ----------------
  const long cb = (long)b * sC;
  if (MODE == 3) {
    // transposed store: Cv[batch][col][row], 2048 rows/batch
#pragma unroll
    for (int mi = 0; mi < 4; ++mi) {
#pragma unroll
      for (int ni = 0; ni < 4; ++ni) {
        const int row0 = bm + wm * 64 + mi * 16 + (lk << 2);
        const int col2 = bn + wn * 64 + ni * 16 + lr;
        const float bvx = HAS_BIAS ? biasB[col2] : 0.f;
        u16x4 pk;
#pragma unroll
        for (int j = 0; j < 4; ++j) pk[j] = f2bf(acc[mi][ni][j] * scale + bvx);
        const long ad = (long)(row0 >> 11) * ((long)N * 2048) +
                        (long)col2 * 2048 + (row0 & 2047);
        *(u16x4*)&((u16*)Cv)[ad] = pk;
      }
    }
  } else {
    // quarter-tile (32 rows) LDS-staged epilogue, 4 passes
    const int q = tid & 7, r = tid >> 3;            // q:0..7, r:0..31
#pragma unroll
    for (int h = 0; h < 4; ++h) {
      __syncthreads();                              // prior LDS use complete
      if (wm == (h >> 1)) {
        const int mi0 = (h & 1) * 2;
#pragma unroll
        for (int mm = 0; mm < 2; ++mm) {
          const int mi = mi0 + mm;
#pragma unroll
          for (int ni = 0; ni < 4; ++ni) {
            const int c = wn * 64 + ni * 16 + lr;
            const float bvx = HAS_BIAS ? biasB[bn + c] : 0.f;
#pragma unroll
            for (int j = 0; j < 4; ++j)
              sm.epi[(mm * 16 + (lk << 2) + j) * 132 + c] =
                  acc[mi][ni][j] * scale + bvx;
          }
        }
      }
      __syncthreads();
      const int growi = bm + h * 32 + r;
      const long grow = cb + (long)growi * N + bn;
      const long mrow = HAS_MASK
          ? ((long)b * sMask + (long)growi * (long)N + bn) : 0;
#pragma unroll
      for (int ch = 0; ch < 2; ++ch) {
        const int c0 = ch * 64 + q * 8;
        const float4 x = *(const float4*)&sm.epi[r * 132 + c0];
        const float4 y = *(const float4*)&sm.epi[r * 132 + c0 + 4];
        if (MODE == 1) {
          *(float4*)&((float*)Cv)[grow + c0] = x;
          *(float4*)&((float*)Cv)[grow + c0 + 4] = y;
        } else {
          u16x8 pk;
          if (HAS_MASK) {
            const int4 ma = *(const int4*)&mask[mrow + c0];
            const int4 mb = *(const int4*)&mask[mrow + c0 + 4];
            pk[0] = f2bf(ma.x ? x.x : -1e30f);
            pk[1] = f2bf(ma.y ? x.y : -1e30f);
            pk[2] = f2bf(ma.z ? x.z : -1e30f);
            pk[3] = f2bf(ma.w ? x.w : -1e30f);
            pk[4] = f2bf(mb.x ? y.x : -1e30f);
            pk[5] = f2bf(mb.y ? y.y : -1e30f);
            pk[6] = f2bf(mb.z ? y.z : -1e30f);
            pk[7] = f2bf(mb.w ? y.w : -1e30f);
          } else {
            pk[0] = f2bf(x.x); pk[1] = f2bf(x.y);
            pk[2] = f2bf(x.z); pk[3] = f2bf(x.w);
            pk[4] = f2bf(y.x); pk[5] = f2bf(y.y);
            pk[6] = f2bf(y.z); pk[7] = f2bf(y.w);
          }
          *(u16x8*)&((u16*)Cv)[grow + c0] = pk;
        }
      }
    }
  }
}

// ---------------------------------------------------------------------------
// Algebraic fusions (torch Linear: x @ W.T + b; softmax over kv axis j):
//   S[q,j] = scale*(q.k) = scale*(query.Mt_row + c_raw[j]) + row-consts
//     where Mt = Wk^T.Wq transposed-combo (qM = query.M, M = Wq^T.Wk),
//     c_raw[j] = kv[j].(Wk^T bq)   (q.bk and bq.bk are per-row -> dropped)
//   out = P.Vw + bvo,  Vw = kv.(Wo.Wv)^T,  bvo = Wo.bv + bo  (since sum P=1)
// ---------------------------------------------------------------------------
extern "C" void kernel_launch(void* const* d_in, const int* in_sizes, int n_in,
                              void* d_out, int out_size, void* d_ws, size_t ws_size,
                              hipStream_t stream) {
  const float* query = (const float*)d_in[0];   // [8,2048,1024]
  const float* kv    = (const float*)d_in[1];   // [8,2048,1024]
  const int*   mask  = (const int*)d_in[2];     // [8,2048,2048]
  const float* Wq = (const float*)d_in[3];
  const float* bq = (const float*)d_in[4];
  const float* Wk = (const float*)d_in[5];
  const float* bk = (const float*)d_in[6];      // unused: softmax-invariant
  const float* Wv = (const float*)d_in[7];
  const float* bv = (const float*)d_in[8];
  const float* Wo = (const float*)d_in[9];
  const float* bo = (const float*)d_in[10];
  float* out = (float*)d_out;
  (void)bk;

  char* ws = (char*)d_ws;
  const size_t MB = (size_t)1 << 20;
  u16* qbf  = (u16*)(ws + 0);          // 32MB query bf16
  u16* kvbf = (u16*)(ws + 32 * MB);    // 32MB kv bf16 (QK B-operand directly)
  u16* wq   = (u16*)(ws + 64 * MB);    // bf16 weights, contiguous 64..72
  u16* wo   = (u16*)(ws + 70 * MB);
  u16* WqT  = (u16*)(ws + 72 * MB);    // 2MB each: Wq^T, Wk^T, Wv^T
  u16* WkT  = (u16*)(ws + 74 * MB);
  u16* WvT  = (u16*)(ws + 76 * MB);
  u16* Mt   = (u16*)(ws + 78 * MB);    // 2MB  Mt[g,f] = (Wq^T.Wk)[f,g]
  u16* Wvo  = (u16*)(ws + 80 * MB);    // 2MB  (Wo.Wv)[f,g]
  float* wvec = (float*)(ws + 82 * MB);  // 4KB  scale*Wk^T.bq
  float* bvo  = (float*)(ws + 82 * MB + 65536);  // 4KB  Wo.bv+bo
  float* cvec = (float*)(ws + 83 * MB);  // 64KB c[8][2048] (pre-scaled)
  u16* qM   = (u16*)(ws + 84 * MB);    // 32MB query.M bf16
  u16* VwT  = (u16*)(ws + 116 * MB);   // 32MB [8][1024][2048]
  u16* S    = (u16*)(ws + 148 * MB);   // 64MB [8][2048][2048] bf16

  const long sQK = (long)2048 * 1024;
  const long sS  = (long)2048 * 2048;

  // 1) converts + weight transposes + bias-vector prep
  cvt_f32_to_bf16<<<8192, 256, 0, stream>>>(query, qbf, 2097152);
  cvt_f32_to_bf16<<<8192, 256, 0, stream>>>(kv, kvbf, 2097152);
  cvt_w4<<<dim3(512, 4, 1), 256, 0, stream>>>(Wq, Wk, Wv, Wo, wq);
  transpose64<<<dim3(16, 16, 3), 256, 0, stream>>>(wq, WqT, 1024, 1024);
  prep_vec<<<8, 256, 0, stream>>>(Wk, bq, Wo, bv, bo, wvec, bvo, 0.03125f);

  // 2) combined weights: Mt = gemm_bt(WkT, WqT); Wvo = gemm_bt(wo, WvT)
  gemm128<false, 0, false><<<dim3(8, 8, 1), 256, 0, stream>>>(
      WkT, WqT, nullptr, nullptr, Mt, 1024, 1024, 1024, 0, 0, 0, 0, 0, 1.f);
  gemm128<false, 0, false><<<dim3(8, 8, 1), 256, 0, stream>>>(
      wo, WvT, nullptr, nullptr, Wvo, 1024, 1024, 1024, 0, 0, 0, 0, 0, 1.f);

  // 3) c[b,j] = scale * kv[b,j].(Wk^T bq)   (wvec pre-scaled)
  cgemv<<<1024, 256, 0, stream>>>(kvbf, wvec, cvec);

  // 4) qM = query.M   (B = Mt, no bias)
  gemm128<false, 0, false><<<dim3(128, 8, 1), 256, 0, stream>>>(
      qbf, Mt, nullptr, nullptr, qM, 16384, 1024, 1024, 0, 0, 0, 0, 0, 1.f);

  // 5) VwT = (kv.Wvo^T) transposed   (MODE 3)
  gemm128<false, 3, false><<<dim3(128, 8, 1), 256, 0, stream>>>(
      kvbf, Wvo, nullptr, nullptr, VwT, 16384, 1024, 1024, 0, 0, 0, 0, 0, 1.f);

  // 6) S = scale*(qM.kv^T) + c[b][j], masked (0 -> -1e30)
  gemm128<true, 0, true><<<dim3(16, 16, 8), 256, 0, stream>>>(
      qM, kvbf, cvec, mask, S, 2048, 2048, 1024, sQK, sQK, sS, sS, 2048,
      0.03125f);

  // 7) row softmax (in place on S)
  softmax_rows<<<16384, 256, 0, stream>>>(S);

  // 8) out = P.Vw + bvo   (fp32 direct to d_out, B = VwT)
  gemm128<true, 1, false><<<dim3(16, 8, 8), 256, 0, stream>>>(
      S, VwT, bvo, nullptr, out, 2048, 1024, 2048, sS, sQK, sQK, 0, 0, 1.f);
}

// Round 11
// 338.132 us; speedup vs baseline: 1.1645x; 1.1645x over previous
//
#include <hip/hip_runtime.h>
#include <hip/hip_bf16.h>
#include <stdint.h>

typedef unsigned short u16;
typedef short s16x8 __attribute__((ext_vector_type(8)));
typedef u16 u16x8 __attribute__((ext_vector_type(8)));
typedef u16 u16x4 __attribute__((ext_vector_type(4)));
typedef float f32x4 __attribute__((ext_vector_type(4)));

__device__ __forceinline__ u16 f2bf(float f) {
  union { float f; uint32_t u; } c; c.f = f;
  uint32_t u = c.u;
  u = u + 0x7fffu + ((u >> 16) & 1u);   // round-to-nearest-even
  return (u16)(u >> 16);
}
__device__ __forceinline__ float bf2f(u16 b) {
  union { uint32_t u; float f; } c; c.u = ((uint32_t)b) << 16;
  return c.f;
}

// async global->LDS, 16B per lane. LDS dest must be wave-uniform base + lane*16.
__device__ __forceinline__ void gld_lds16(const u16* g, u16* l) {
  __builtin_amdgcn_global_load_lds(
      (const __attribute__((address_space(1))) uint32_t*)g,
      (__attribute__((address_space(3))) uint32_t*)l,
      16, 0, 0);
}

// ---------------------------------------------------------------------------
// fp32 -> bf16 convert, 8 elems/thread
// ---------------------------------------------------------------------------
__global__ __launch_bounds__(256) void cvt_f32_to_bf16(
    const float* __restrict__ in, u16* __restrict__ out, long n8) {
  long i = (long)blockIdx.x * blockDim.x + threadIdx.x;
  if (i >= n8) return;
  const float4 a = ((const float4*)in)[i * 2];
  const float4 b = ((const float4*)in)[i * 2 + 1];
  u16x8 r;
  r[0] = f2bf(a.x); r[1] = f2bf(a.y); r[2] = f2bf(a.z); r[3] = f2bf(a.w);
  r[4] = f2bf(b.x); r[5] = f2bf(b.y); r[6] = f2bf(b.z); r[7] = f2bf(b.w);
  *(u16x8*)&out[i * 8] = r;
}

// 4 weight matrices (1024x1024 each) in one launch: blockIdx.y selects src
__global__ __launch_bounds__(256) void cvt_w4(
    const float* __restrict__ w0, const float* __restrict__ w1,
    const float* __restrict__ w2, const float* __restrict__ w3,
    u16* __restrict__ out) {
  const float* src = (blockIdx.y == 0) ? w0 : (blockIdx.y == 1) ? w1
                   : (blockIdx.y == 2) ? w2 : w3;
  const long i = (long)blockIdx.x * blockDim.x + threadIdx.x;
  const float4 a = ((const float4*)src)[i * 2];
  const float4 b = ((const float4*)src)[i * 2 + 1];
  u16x8 r;
  r[0] = f2bf(a.x); r[1] = f2bf(a.y); r[2] = f2bf(a.z); r[3] = f2bf(a.w);
  r[4] = f2bf(b.x); r[5] = f2bf(b.y); r[6] = f2bf(b.z); r[7] = f2bf(b.w);
  *(u16x8*)&out[(long)blockIdx.y * 1048576 + i * 8] = r;
}

// ---------------------------------------------------------------------------
// bf16 tiled transpose: in [z][R][C] -> out [z][C][R], 64x64 tiles
// ---------------------------------------------------------------------------
__global__ __launch_bounds__(256) void transpose64(
    const u16* __restrict__ in, u16* __restrict__ out, int R, int C) {
  __shared__ u16 t[64][66];
  const long ib = (long)blockIdx.z * (long)R * C;
  const int r0 = blockIdx.x * 64, c0 = blockIdx.y * 64;
  const int tid = threadIdx.x;
#pragma unroll
  for (int i = 0; i < 2; ++i) {
    const int ch = i * 256 + tid;
    const int r = ch >> 3, cc = ch & 7;
    const s16x8 v = *(const s16x8*)&in[ib + (long)(r0 + r) * C + c0 + cc * 8];
#pragma unroll
    for (int j = 0; j < 8; ++j) t[r][cc * 8 + j] = (u16)v[j];
  }
  __syncthreads();
#pragma unroll
  for (int i = 0; i < 2; ++i) {
    const int ch = i * 256 + tid;
    const int c = ch >> 3, rr = ch & 7;
    u16x8 r8;
#pragma unroll
    for (int j = 0; j < 8; ++j) r8[j] = t[rr * 8 + j][c];
    *(u16x8*)&out[ib + (long)(c0 + c) * R + r0 + rr * 8] = r8;
  }
}

// ---------------------------------------------------------------------------
// dual GEMV over bf16 matrix rows, 16 rows/block:
//  blocks 0-63:   outA[r] = scaleA * dot(matA[r,:], vecA)        (wvec)
//  blocks 64-127: outB[r] = dot(matB[r,:], vecB) + addB[r]       (bvo)
// ---------------------------------------------------------------------------
__global__ __launch_bounds__(256) void bgemv(
    const u16* __restrict__ matA, const float* __restrict__ vecA,
    const u16* __restrict__ matB, const float* __restrict__ vecB,
    const float* __restrict__ addB, float* __restrict__ outA,
    float* __restrict__ outB, float scaleA) {
  __shared__ float w[1024];
  const int tid = threadIdx.x;
  const bool second = blockIdx.x >= 64;
  const u16* mat = second ? matB : matA;
  const float* vec = second ? vecB : vecA;
  const int rb = (second ? (int)blockIdx.x - 64 : (int)blockIdx.x) * 16;
#pragma unroll
  for (int i = 0; i < 4; ++i) w[i * 256 + tid] = vec[i * 256 + tid];
  __syncthreads();
  const int lane = tid & 63, wv_ = tid >> 6;
#pragma unroll
  for (int r = 0; r < 4; ++r) {
    const int row = rb + wv_ * 4 + r;
    const u16* p = &mat[(long)row * 1024 + lane * 16];
    const u16x8 a = *(const u16x8*)p;
    const u16x8 b = *(const u16x8*)(p + 8);
    float s = 0.f;
#pragma unroll
    for (int j = 0; j < 8; ++j) s += bf2f(a[j]) * w[lane * 16 + j];
#pragma unroll
    for (int j = 0; j < 8; ++j) s += bf2f(b[j]) * w[lane * 16 + 8 + j];
#pragma unroll
    for (int off = 32; off >= 1; off >>= 1) s += __shfl_xor(s, off);
    if (lane == 0) {
      if (second) outB[row] = s + addB[row];
      else        outA[row] = s * scaleA;
    }
  }
}

// ---------------------------------------------------------------------------
// c[row] = dot(kvbf[row, :1024], wvec)  — 16 rows/block (wvec pre-scaled)
// ---------------------------------------------------------------------------
__global__ __launch_bounds__(256) void cgemv(
    const u16* __restrict__ kvbf, const float* __restrict__ wvec,
    float* __restrict__ c) {
  __shared__ float w[1024];
  const int tid = threadIdx.x;
#pragma unroll
  for (int i = 0; i < 4; ++i) w[i * 256 + tid] = wvec[i * 256 + tid];
  __syncthreads();
  const int lane = tid & 63, wv_ = tid >> 6;
  const long rowbase = (long)blockIdx.x * 16 + wv_ * 4;
#pragma unroll
  for (int r = 0; r < 4; ++r) {
    const long row = rowbase + r;
    const u16* p = &kvbf[row * 1024 + lane * 16];
    const u16x8 a = *(const u16x8*)p;
    const u16x8 b = *(const u16x8*)(p + 8);
    float s = 0.f;
#pragma unroll
    for (int j = 0; j < 8; ++j) s += bf2f(a[j]) * w[lane * 16 + j];
#pragma unroll
    for (int j = 0; j < 8; ++j) s += bf2f(b[j]) * w[lane * 16 + 8 + j];
#pragma unroll
    for (int off = 32; off >= 1; off >>= 1) s += __shfl_xor(s, off);
    if (lane == 0) c[row] = s;
  }
}

// ---------------------------------------------------------------------------
// row softmax over 2048 cols, bf16 in/out (in place), fp32 math.
// S already has -1e30 at masked positions (mask fused into QK epilogue).
// ---------------------------------------------------------------------------
__global__ __launch_bounds__(256) void softmax_rows(u16* __restrict__ S) {
  const long base = (long)blockIdx.x * 2048;
  const int tid = threadIdx.x;
  const int lane = tid & 63, wave = tid >> 6;
  u16x8 raw = *(const u16x8*)&S[base + tid * 8];
  float v[8];
#pragma unroll
  for (int j = 0; j < 8; ++j) v[j] = bf2f(raw[j]);
  float m = v[0];
#pragma unroll
  for (int j = 1; j < 8; ++j) m = fmaxf(m, v[j]);
#pragma unroll
  for (int off = 32; off >= 1; off >>= 1) m = fmaxf(m, __shfl_xor(m, off));
  __shared__ float red[8];
  if (lane == 0) red[wave] = m;
  __syncthreads();
  m = fmaxf(fmaxf(red[0], red[1]), fmaxf(red[2], red[3]));
  float s = 0.f;
#pragma unroll
  for (int j = 0; j < 8; ++j) { v[j] = __expf(v[j] - m); s += v[j]; }
#pragma unroll
  for (int off = 32; off >= 1; off >>= 1) s += __shfl_xor(s, off);
  if (lane == 0) red[4 + wave] = s;
  __syncthreads();
  s = (red[4] + red[5]) + (red[6] + red[7]);
  const float inv = 1.f / s;
#pragma unroll
  for (int j = 0; j < 8; ++j) raw[j] = f2bf(v[j] * inv);
  *(u16x8*)&S[base + tid * 8] = raw;
}

// ---------------------------------------------------------------------------
// 128x128x64 GEMM (bt), m97/m103 TLP structure (round-7/9 verified ~890 TF):
// 256 thr = 4 waves (2x2), single-buffered 32 KiB LDS, 2 barriers/K-tile,
// 5 blocks/CU via LDS limit; __launch_bounds__(256,4) (VGPR 64, no spill).
// T2 chunk-XOR swizzle (0 read conflicts), T1 XCD-bijective remap.
// MODE: 0 bf16 out; 1 f32 out. bias[col] per-batch stride sBias; optional
// fused mask (0 -> -1e30). Batched via sA/sB/sC (negative strides legal —
// used for the merged weight-GEMM pointer trick).
// ---------------------------------------------------------------------------
union __align__(16) SmemT {
  u16 stage[2][128 * 64];        // 32 KiB: A-tile, B-tile
  float epi[32 * 132];           // 16.9 KiB epilogue C-staging (quarter-tile)
};

__device__ __forceinline__ s16x8 ldsfrag(const u16* p, int r, int c8) {
  return *(const s16x8*)&p[r * 64 + ((c8 ^ (r & 7)) << 3)];
}

__device__ __forceinline__ void stage128(const u16* __restrict__ gb, int row0,
                                         int K, int k0, u16* lbuf, int tid) {
#pragma unroll
  for (int i = 0; i < 4; ++i) {
    const int f = i * 256 + tid;
    const int rl = f >> 3, s = f & 7;
    const int gc = (s ^ (rl & 7)) << 3;     // pre-swizzled global col chunk
    gld_lds16(gb + (long)(row0 + rl) * K + k0 + gc, lbuf + f * 8);
  }
}

template<bool HAS_BIAS, int MODE, bool HAS_MASK>
__global__ __launch_bounds__(256, 4) void gemm128(
    const u16* __restrict__ A, const u16* __restrict__ B,
    const float* __restrict__ bias, const int* __restrict__ mask,
    void* __restrict__ Cv,
    int M, int N, int K, long sA, long sB, long sC, long sMask, long sBias,
    float scale) {
  __shared__ SmemT sm;
  // T1 swizzle: dispatch id -> XCD-contiguous chunk (z-major, then m, then n)
  const int nx = gridDim.x, ny = gridDim.y;
  const int did = blockIdx.x + nx * (blockIdx.y + ny * blockIdx.z);
  const int cpx = (nx * ny * gridDim.z) >> 3;       // all grids %8 == 0
  const int nf = (did & 7) * cpx + (did >> 3);
  const int b = nf / (nx * ny);
  const int rr = nf % (nx * ny);
  const int bm = (rr / ny) * 128;
  const int bn = (rr % ny) * 128;

  const u16* Ab = A + (long)b * sA;
  const u16* Bb = B + (long)b * sB;
  const float* biasB = HAS_BIAS ? (bias + (long)b * sBias) : nullptr;
  const int tid = threadIdx.x;
  const int lane = tid & 63, wave = tid >> 6;
  const int wm = wave >> 1, wn = wave & 1;          // 2x2 waves, 64x64 each
  const int lr = lane & 15, lk = lane >> 4;
  const int NT = K >> 6;

  f32x4 acc[4][4] = {};

  for (int t = 0; t < NT; ++t) {
    stage128(Ab, bm, K, t << 6, sm.stage[0], tid);
    stage128(Bb, bn, K, t << 6, sm.stage[1], tid);
    asm volatile("s_waitcnt vmcnt(0)" ::: "memory");
    __syncthreads();
#pragma unroll
    for (int ks = 0; ks < 2; ++ks) {
      s16x8 af[4], bg[4];
#pragma unroll
      for (int mi = 0; mi < 4; ++mi)
        af[mi] = ldsfrag(sm.stage[0], wm * 64 + mi * 16 + lr, ks * 4 + lk);
#pragma unroll
      for (int ni = 0; ni < 4; ++ni)
        bg[ni] = ldsfrag(sm.stage[1], wn * 64 + ni * 16 + lr, ks * 4 + lk);
#pragma unroll
      for (int mi = 0; mi < 4; ++mi)
#pragma unroll
        for (int ni = 0; ni < 4; ++ni)
          acc[mi][ni] = __builtin_amdgcn_mfma_f32_16x16x32_bf16(
              af[mi], bg[ni], acc[mi][ni], 0, 0, 0);
    }
    __syncthreads();
  }

  // ---------------- epilogue: quarter-tile LDS-staged, 4 passes ----------
  const long cb = (long)b * sC;
  const int q = tid & 7, r = tid >> 3;              // q:0..7, r:0..31
#pragma unroll
  for (int h = 0; h < 4; ++h) {
    __syncthreads();                                // prior LDS use complete
    if (wm == (h >> 1)) {
      const int mi0 = (h & 1) * 2;
#pragma unroll
      for (int mm = 0; mm < 2; ++mm) {
        const int mi = mi0 + mm;
#pragma unroll
        for (int ni = 0; ni < 4; ++ni) {
          const int c = wn * 64 + ni * 16 + lr;
          const float bvx = HAS_BIAS ? biasB[bn + c] : 0.f;
#pragma unroll
          for (int j = 0; j < 4; ++j)
            sm.epi[(mm * 16 + (lk << 2) + j) * 132 + c] =
                acc[mi][ni][j] * scale + bvx;
        }
      }
    }
    __syncthreads();
    const int growi = bm + h * 32 + r;
    const long grow = cb + (long)growi * N + bn;
    const long mrow = HAS_MASK
        ? ((long)b * sMask + (long)growi * (long)N + bn) : 0;
#pragma unroll
    for (int ch = 0; ch < 2; ++ch) {
      const int c0 = ch * 64 + q * 8;
      const float4 x = *(const float4*)&sm.epi[r * 132 + c0];
      const float4 y = *(const float4*)&sm.epi[r * 132 + c0 + 4];
      if (MODE == 1) {
        *(float4*)&((float*)Cv)[grow + c0] = x;
        *(float4*)&((float*)Cv)[grow + c0 + 4] = y;
      } else {
        u16x8 pk;
        if (HAS_MASK) {
          const int4 ma = *(const int4*)&mask[mrow + c0];
          const int4 mb = *(const int4*)&mask[mrow + c0 + 4];
          pk[0] = f2bf(ma.x ? x.x : -1e30f);
          pk[1] = f2bf(ma.y ? x.y : -1e30f);
          pk[2] = f2bf(ma.z ? x.z : -1e30f);
          pk[3] = f2bf(ma.w ? x.w : -1e30f);
          pk[4] = f2bf(mb.x ? y.x : -1e30f);
          pk[5] = f2bf(mb.y ? y.y : -1e30f);
          pk[6] = f2bf(mb.z ? y.z : -1e30f);
          pk[7] = f2bf(mb.w ? y.w : -1e30f);
        } else {
          pk[0] = f2bf(x.x); pk[1] = f2bf(x.y);
          pk[2] = f2bf(x.z); pk[3] = f2bf(x.w);
          pk[4] = f2bf(y.x); pk[5] = f2bf(y.y);
          pk[6] = f2bf(y.z); pk[7] = f2bf(y.w);
        }
        *(u16x8*)&((u16*)Cv)[grow + c0] = pk;
      }
    }
  }
}

// ---------------------------------------------------------------------------
// Algebraic fusions (torch Linear: x @ W.T + b; softmax over kv axis j):
//   S[q,j] = scale*(query.M)[q,:].kv[j,:] + c[j] (+ row-consts dropped),
//     M = Wq^T.Wk (as Mt = gemm_bt(WkT, WqT)), c[j] = scale*kv[j].(Wk^T bq)
//   out = P.Vw + bvo,  Vw^T = gemm_bt(Wvo, kv) (Wvo = Wo.Wv),
//   bvo = Wo.bv + bo   (valid since sum_j P = 1)
// ---------------------------------------------------------------------------
extern "C" void kernel_launch(void* const* d_in, const int* in_sizes, int n_in,
                              void* d_out, int out_size, void* d_ws, size_t ws_size,
                              hipStream_t stream) {
  const float* query = (const float*)d_in[0];   // [8,2048,1024]
  const float* kv    = (const float*)d_in[1];   // [8,2048,1024]
  const int*   mask  = (const int*)d_in[2];     // [8,2048,2048]
  const float* Wq = (const float*)d_in[3];
  const float* bq = (const float*)d_in[4];
  const float* Wk = (const float*)d_in[5];
  const float* bk = (const float*)d_in[6];      // unused: softmax-invariant
  const float* Wv = (const float*)d_in[7];
  const float* bv = (const float*)d_in[8];
  const float* Wo = (const float*)d_in[9];
  const float* bo = (const float*)d_in[10];
  float* out = (float*)d_out;
  (void)bk;

  char* ws = (char*)d_ws;
  const size_t MB = (size_t)1 << 20;
  u16* qbf  = (u16*)(ws + 0);          // 32MB query bf16
  u16* kvbf = (u16*)(ws + 32 * MB);    // 32MB kv bf16 (QK B-operand directly)
  u16* wq   = (u16*)(ws + 64 * MB);    // bf16 weights contiguous: wq,wk,wv,wo
  u16* wo   = (u16*)(ws + 70 * MB);
  u16* WqT  = (u16*)(ws + 72 * MB);    // 2MB each: Wq^T, Wk^T, Wv^T
  u16* WkT  = (u16*)(ws + 74 * MB);
  u16* Mt   = (u16*)(ws + 78 * MB);    // 2MB  Mt = gemm_bt(WkT, WqT)
  u16* Wvo  = (u16*)(ws + 80 * MB);    // 2MB  Wo.Wv
  float* wvec = (float*)(ws + 82 * MB);             // 4KB scale*Wk^T.bq
  float* bvo  = (float*)(ws + 82 * MB + 65536);     // 4KB Wo.bv+bo
  float* cvec = (float*)(ws + 83 * MB);             // 64KB c[8][2048]
  u16* qM   = (u16*)(ws + 84 * MB);    // 32MB query.M bf16
  u16* VwT  = (u16*)(ws + 116 * MB);   // 32MB [8][1024][2048]
  u16* S    = (u16*)(ws + 148 * MB);   // 64MB [8][2048][2048] bf16

  const long sQK = (long)2048 * 1024;
  const long sS  = (long)2048 * 2048;

  // 1) converts + weight transposes + vector prep
  cvt_f32_to_bf16<<<8192, 256, 0, stream>>>(query, qbf, 2097152);
  cvt_f32_to_bf16<<<8192, 256, 0, stream>>>(kv, kvbf, 2097152);
  cvt_w4<<<dim3(512, 4, 1), 256, 0, stream>>>(Wq, Wk, Wv, Wo, wq);
  transpose64<<<dim3(16, 16, 3), 256, 0, stream>>>(wq, WqT, 1024, 1024);
  bgemv<<<128, 256, 0, stream>>>(WkT, bq, wo, bv, bo, wvec, bvo, 0.03125f);
  cgemv<<<1024, 256, 0, stream>>>(kvbf, wvec, cvec);

  // 2) merged weight GEMMs (one batched launch, pointer-stride trick):
  //    z=0: Mt  = gemm_bt(WkT, WqT);  z=1: Wvo = gemm_bt(wo, WvT)
  //    sA: WkT->wo = -2 MB; sB: WqT->WvT = +4 MB; sC: Mt->Wvo = +2 MB
  gemm128<false, 0, false><<<dim3(8, 8, 2), 256, 0, stream>>>(
      WkT, WqT, nullptr, nullptr, Mt, 1024, 1024, 1024,
      -2097152L, 2097152L, 1048576L, 0, 0, 1.f);

  // 3) qM = query.M
  gemm128<false, 0, false><<<dim3(128, 8, 1), 256, 0, stream>>>(
      qbf, Mt, nullptr, nullptr, qM, 16384, 1024, 1024, 0, 0, 0, 0, 0, 1.f);

  // 4) VwT[b][f][j] = gemm_bt(A=Wvo shared, B=kv[b])  (direct, no transpose)
  gemm128<false, 0, false><<<dim3(8, 16, 8), 256, 0, stream>>>(
      Wvo, kvbf, nullptr, nullptr, VwT, 1024, 2048, 1024,
      0, sQK, sQK, 0, 0, 1.f);

  // 5) S = scale*(qM.kv^T) + c[b][j], masked (0 -> -1e30)
  gemm128<true, 0, true><<<dim3(16, 16, 8), 256, 0, stream>>>(
      qM, kvbf, cvec, mask, S, 2048, 2048, 1024, sQK, sQK, sS, sS, 2048,
      0.03125f);

  // 6) row softmax (in place on S)
  softmax_rows<<<16384, 256, 0, stream>>>(S);

  // 7) out = P.Vw + bvo   (fp32 direct to d_out, B = VwT)
  gemm128<true, 1, false><<<dim3(16, 8, 8), 256, 0, stream>>>(
      S, VwT, bvo, nullptr, out, 2048, 1024, 2048, sS, sQK, sQK, 0, 0, 1.f);
}